// Round 6
// baseline (146.958 us; speedup 1.0000x reference)
//
#include <hip/hip_runtime.h>
#include <hip/hip_bf16.h>

#define NN 8192
#define DD 128
#define BM 16
#define JS 8            // j-slices (K-split of the reduction), XCD-affine

typedef __attribute__((ext_vector_type(4))) float f32x4;
typedef __attribute__((ext_vector_type(8))) short bf16x8;

__device__ __forceinline__ unsigned short f2bf(float x) {
    unsigned u = __float_as_uint(x);
    u += 0x7fffu + ((u >> 16) & 1u);   // round-to-nearest-even
    return (unsigned short)(u >> 16);
}

// ---------------------------------------------------------------------------
// Kernel A: hT[n][j] = bf16( B[n] + sum_k z[j][k] * W[k][n] ), plain layout.
// ---------------------------------------------------------------------------
__global__ void __launch_bounds__(256) h_transform(
    const float* __restrict__ z, const float* __restrict__ W,
    const float* __restrict__ Bv, unsigned short* __restrict__ hT) {
    __shared__ float zs[BM * DD];
    __shared__ float wt[DD * 132];
    const int t = threadIdx.x;
    const int j0 = blockIdx.x * BM;

    {
        const f32x4* zsrc = (const f32x4*)(z + (size_t)j0 * DD);
        f32x4* zdst = (f32x4*)zs;
        zdst[t] = zsrc[t];
        zdst[t + 256] = zsrc[t + 256];
    }
    for (int q = t; q < DD * 32; q += 256) {
        int k = q >> 5;
        int n0 = (q & 31) << 2;
        f32x4 wv = *(const f32x4*)(W + k * DD + n0);
        wt[(n0 + 0) * 132 + k] = wv[0];
        wt[(n0 + 1) * 132 + k] = wv[1];
        wt[(n0 + 2) * 132 + k] = wv[2];
        wt[(n0 + 3) * 132 + k] = wv[3];
    }
    __syncthreads();

    const int n = t >> 1;
    const int ja = (t & 1) << 3;
    float acc[8];
    float bn = Bv[n];
#pragma unroll
    for (int e = 0; e < 8; e++) acc[e] = bn;

#pragma unroll 8
    for (int k4 = 0; k4 < 32; ++k4) {
        f32x4 wv = *(const f32x4*)&wt[n * 132 + (k4 << 2)];
#pragma unroll
        for (int e = 0; e < 8; e++) {
            f32x4 zv = *(const f32x4*)&zs[(ja + e) * DD + (k4 << 2)];
            acc[e] += zv[0] * wv[0] + zv[1] * wv[1] + zv[2] * wv[2] + zv[3] * wv[3];
        }
    }

    const int j = j0 + ja;
    unsigned short* dst = hT + (size_t)n * NN + j;
    uint4 uv;
    uv.x = (unsigned)f2bf(acc[0]) | ((unsigned)f2bf(acc[1]) << 16);
    uv.y = (unsigned)f2bf(acc[2]) | ((unsigned)f2bf(acc[3]) << 16);
    uv.z = (unsigned)f2bf(acc[4]) | ((unsigned)f2bf(acc[5]) << 16);
    uv.w = (unsigned)f2bf(acc[6]) | ((unsigned)f2bf(acc[7]) << 16);
    *(uint4*)dst = uv;
}

// ---------------------------------------------------------------------------
// Kernel B: barrier-free fused S + S@h with EXPLICIT deep prefetch rotation.
// One wave per block; 32 rows x 128 n; K-range [ks*1024, +1024) = 32 groups
// of K=32. dist prefetched 3 groups ahead (4 named slots), hT 2 groups ahead
// (2 named slots); sched_barrier(0) pins load-issue before each COMPUTE so
// the scheduler cannot collapse liveness (R4 evidence: VGPR=96 -> only ~half
// a group in flight -> 2 TB/s). ks = bid&7 gives XCD-affine hT L2 slices.
// ---------------------------------------------------------------------------
__device__ __forceinline__ bf16x8 sfrag(f32x4 a, f32x4 b, int jbase, int diag,
                                        float inv_mu, float ninv2s2) {
    float v0[4] = {a[0], a[1], a[2], a[3]};
    float v1[4] = {b[0], b[1], b[2], b[3]};
    unsigned short h[8];
#pragma unroll
    for (int e = 0; e < 4; ++e) {
        float d = v0[e];
        float q = __builtin_amdgcn_rcpf(d) - inv_mu;
        float s = __expf(q * q * ninv2s2);
        bool keep = (d < 0.5f) & ((jbase + e) != diag);
        h[e] = f2bf(keep ? s : 0.0f);
    }
#pragma unroll
    for (int e = 0; e < 4; ++e) {
        float d = v1[e];
        float q = __builtin_amdgcn_rcpf(d) - inv_mu;
        float s = __expf(q * q * ninv2s2);
        bool keep = (d < 0.5f) & ((jbase + 4 + e) != diag);
        h[4 + e] = f2bf(keep ? s : 0.0f);
    }
    uint4 u;
    u.x = (unsigned)h[0] | ((unsigned)h[1] << 16);
    u.y = (unsigned)h[2] | ((unsigned)h[3] << 16);
    u.z = (unsigned)h[4] | ((unsigned)h[5] << 16);
    u.w = (unsigned)h[6] | ((unsigned)h[7] << 16);
    return __builtin_bit_cast(bf16x8, u);
}

__global__ void __launch_bounds__(64, 2) fused_interact(
    const float* __restrict__ dist, const unsigned short* __restrict__ hT,
    const float* __restrict__ mu, const float* __restrict__ sigma,
    float* __restrict__ part) {
    const int l = threadIdx.x;
    const int ks = (int)blockIdx.x & 7;        // XCD-affine j-slice
    const int rt = (int)blockIdx.x >> 3;       // 0..255
    const int kbeg = ks * (NN / JS);
    const int r0 = rt * 32;

    const int row = l & 15;
    const int kc8 = (l >> 4) << 3;

    const float inv_mu = 1.0f / mu[0];
    const float sg = sigma[0];
    const float ninv2s2 = -1.0f / (2.0f * sg * sg);

    const float* dp0 = dist + (size_t)(r0 + row) * NN + kc8;
    const float* dp1 = dp0 + (size_t)16 * NN;
    const unsigned short* hp = hT + (size_t)row * NN + kc8;
    const int diag0 = r0 + row;
    const int diag1 = diag0 + 16;

    f32x4 acc[2][8];
#pragma unroll
    for (int m = 0; m < 2; ++m)
#pragma unroll
        for (int f = 0; f < 8; ++f) acc[m][f] = (f32x4){0.f, 0.f, 0.f, 0.f};

    // named prefetch slots: dist depth 4 (use 3 ahead), hT depth 2
    f32x4 s0a, s0b, s0c, s0d, s1a, s1b, s1c, s1d;
    f32x4 s2a, s2b, s2c, s2d, s3a, s3b, s3c, s3d;
    uint4 h0[8], h1[8];

#define LD_DIST(S, K)                                                        \
    do {                                                                     \
        S##a = *(const f32x4*)(dp0 + (K));                                   \
        S##b = *(const f32x4*)(dp0 + (K) + 4);                               \
        S##c = *(const f32x4*)(dp1 + (K));                                   \
        S##d = *(const f32x4*)(dp1 + (K) + 4);                               \
    } while (0)

#define LD_HT(H, K)                                                          \
    do {                                                                     \
        _Pragma("unroll") for (int f = 0; f < 8; ++f)                        \
            H[f] = *(const uint4*)(hp + (size_t)f * 16 * NN + (K));          \
    } while (0)

#define COMPUTE(S, H, K)                                                     \
    do {                                                                     \
        bf16x8 a0 = sfrag(S##a, S##b, (K) + kc8, diag0, inv_mu, ninv2s2);    \
        bf16x8 a1 = sfrag(S##c, S##d, (K) + kc8, diag1, inv_mu, ninv2s2);    \
        _Pragma("unroll") for (int f = 0; f < 8; ++f) {                      \
            bf16x8 bb = __builtin_bit_cast(bf16x8, H[f]);                    \
            acc[0][f] = __builtin_amdgcn_mfma_f32_16x16x32_bf16(             \
                a0, bb, acc[0][f], 0, 0, 0);                                 \
            acc[1][f] = __builtin_amdgcn_mfma_f32_16x16x32_bf16(             \
                a1, bb, acc[1][f], 0, 0, 0);                                 \
        }                                                                    \
    } while (0)

    // prologue: groups 0..2 dist, 0..1 hT
    LD_DIST(s0, kbeg);
    LD_DIST(s1, kbeg + 32);
    LD_DIST(s2, kbeg + 64);
    LD_HT(h0, kbeg);
    LD_HT(h1, kbeg + 32);

#pragma unroll 1
    for (int g = 0; g < 32; g += 4) {
        const int kb = kbeg + g * 32;
        // sub 0: consume (s0, h0) = group g
        if (g + 3 < 32) LD_DIST(s3, kb + 96);
        __builtin_amdgcn_sched_barrier(0);
        COMPUTE(s0, h0, kb);
        if (g + 2 < 32) LD_HT(h0, kb + 64);
        // sub 1: consume (s1, h1) = group g+1
        if (g + 4 < 32) LD_DIST(s0, kb + 128);
        __builtin_amdgcn_sched_barrier(0);
        COMPUTE(s1, h1, kb + 32);
        if (g + 3 < 32) LD_HT(h1, kb + 96);
        // sub 2: consume (s2, h0) = group g+2
        if (g + 5 < 32) LD_DIST(s1, kb + 160);
        __builtin_amdgcn_sched_barrier(0);
        COMPUTE(s2, h0, kb + 64);
        if (g + 4 < 32) LD_HT(h0, kb + 128);
        // sub 3: consume (s3, h1) = group g+3
        if (g + 6 < 32) LD_DIST(s2, kb + 192);
        __builtin_amdgcn_sched_barrier(0);
        COMPUTE(s3, h1, kb + 96);
        if (g + 5 < 32) LD_HT(h1, kb + 160);
    }
#undef LD_DIST
#undef LD_HT
#undef COMPUTE

    // epilogue (validated C-layout: col = lane&15, row = (lane>>4)*4 + rr)
    float* po = part + (size_t)ks * (NN * DD);
    const int orow = r0 + ((l >> 4) << 2);
    const int ocol = l & 15;
#pragma unroll
    for (int m = 0; m < 2; ++m)
#pragma unroll
        for (int f = 0; f < 8; ++f)
#pragma unroll
            for (int rr = 0; rr < 4; ++rr)
                po[(size_t)(orow + m * 16 + rr) * DD + f * 16 + ocol] =
                    acc[m][f][rr];
}

// ---------------------------------------------------------------------------
// Kernel C: sum the 8 K-split partials into out.
// ---------------------------------------------------------------------------
__global__ void __launch_bounds__(256) reduce_part(
    const float* __restrict__ part, float* __restrict__ outp) {
    const size_t idx = ((size_t)blockIdx.x * 256 + threadIdx.x) << 2;
    f32x4 s = *(const f32x4*)(part + idx);
#pragma unroll
    for (int ksp = 1; ksp < JS; ++ksp)
        s += *(const f32x4*)(part + (size_t)ksp * (NN * DD) + idx);
    *(f32x4*)(outp + idx) = s;
}

extern "C" void kernel_launch(void* const* d_in, const int* in_sizes, int n_in,
                              void* d_out, int out_size, void* d_ws, size_t ws_size,
                              hipStream_t stream) {
    const float* z = (const float*)d_in[0];
    const float* dist = (const float*)d_in[1];
    const float* W = (const float*)d_in[2];
    const float* Bv = (const float*)d_in[3];
    const float* mu = (const float*)d_in[4];
    const float* sigma = (const float*)d_in[5];
    float* out = (float*)d_out;

    unsigned short* hT = (unsigned short*)d_ws;                 // 2 MB
    const size_t hT_bytes = (size_t)DD * NN * 2;
    float* part = (float*)((char*)d_ws + hT_bytes);             // 8 x 4 MB

    h_transform<<<NN / BM, 256, 0, stream>>>(z, W, Bv, hT);
    fused_interact<<<(NN / 32) * JS, 64, 0, stream>>>(dist, hT, mu, sigma,
                                                      part);
    reduce_part<<<(NN * DD) / 1024, 256, 0, stream>>>(part, out);
}

// Round 7
// 140.090 us; speedup vs baseline: 1.0490x; 1.0490x over previous
//
#include <hip/hip_runtime.h>
#include <hip/hip_bf16.h>

#define NN 8192
#define DD 128
#define BM 16
#define JS 8            // j-slices (K-split of the reduction), XCD-affine

typedef __attribute__((ext_vector_type(4))) float f32x4;
typedef __attribute__((ext_vector_type(8))) short bf16x8;

__device__ __forceinline__ unsigned short f2bf(float x) {
    unsigned u = __float_as_uint(x);
    u += 0x7fffu + ((u >> 16) & 1u);   // round-to-nearest-even
    return (unsigned short)(u >> 16);
}

// ---------------------------------------------------------------------------
// Kernel A: hT[n][j] = bf16( B[n] + sum_k z[j][k] * W[k][n] ), plain layout.
// ---------------------------------------------------------------------------
__global__ void __launch_bounds__(256) h_transform(
    const float* __restrict__ z, const float* __restrict__ W,
    const float* __restrict__ Bv, unsigned short* __restrict__ hT) {
    __shared__ float zs[BM * DD];
    __shared__ float wt[DD * 132];
    const int t = threadIdx.x;
    const int j0 = blockIdx.x * BM;

    {
        const f32x4* zsrc = (const f32x4*)(z + (size_t)j0 * DD);
        f32x4* zdst = (f32x4*)zs;
        zdst[t] = zsrc[t];
        zdst[t + 256] = zsrc[t + 256];
    }
    for (int q = t; q < DD * 32; q += 256) {
        int k = q >> 5;
        int n0 = (q & 31) << 2;
        f32x4 wv = *(const f32x4*)(W + k * DD + n0);
        wt[(n0 + 0) * 132 + k] = wv[0];
        wt[(n0 + 1) * 132 + k] = wv[1];
        wt[(n0 + 2) * 132 + k] = wv[2];
        wt[(n0 + 3) * 132 + k] = wv[3];
    }
    __syncthreads();

    const int n = t >> 1;
    const int ja = (t & 1) << 3;
    float acc[8];
    float bn = Bv[n];
#pragma unroll
    for (int e = 0; e < 8; e++) acc[e] = bn;

#pragma unroll 8
    for (int k4 = 0; k4 < 32; ++k4) {
        f32x4 wv = *(const f32x4*)&wt[n * 132 + (k4 << 2)];
#pragma unroll
        for (int e = 0; e < 8; e++) {
            f32x4 zv = *(const f32x4*)&zs[(ja + e) * DD + (k4 << 2)];
            acc[e] += zv[0] * wv[0] + zv[1] * wv[1] + zv[2] * wv[2] + zv[3] * wv[3];
        }
    }

    const int j = j0 + ja;
    unsigned short* dst = hT + (size_t)n * NN + j;
    uint4 uv;
    uv.x = (unsigned)f2bf(acc[0]) | ((unsigned)f2bf(acc[1]) << 16);
    uv.y = (unsigned)f2bf(acc[2]) | ((unsigned)f2bf(acc[3]) << 16);
    uv.z = (unsigned)f2bf(acc[4]) | ((unsigned)f2bf(acc[5]) << 16);
    uv.w = (unsigned)f2bf(acc[6]) | ((unsigned)f2bf(acc[7]) << 16);
    *(uint4*)dst = uv;
}

// ---------------------------------------------------------------------------
// Kernel B: barrier-free fused S + S@h, BRANCH-FREE steady-state pipeline.
// One wave per block; 32 rows x 128 n; K-range = 32 groups of K=32.
// Depth-2 register rotation with UNCONDITIONAL loads in the loop body and a
// peeled no-load tail: conditional VMEM issue (R2/R6) forced SIInsertWaitcnts
// into conservative vmcnt(~0) before every consumer -> each group serialized
// at full HBM latency -> the ~1.2 TB/s wall seen in every prior round.
// Branch-free body lets the waitcnt pass count precisely (vmcnt(12/20)),
// keeping ~1.5 groups in flight per wave, 8 waves/CU.
// ---------------------------------------------------------------------------
__device__ __forceinline__ bf16x8 sfrag(f32x4 a, f32x4 b, int jbase, int diag,
                                        float inv_mu, float ninv2s2) {
    float v0[4] = {a[0], a[1], a[2], a[3]};
    float v1[4] = {b[0], b[1], b[2], b[3]};
    unsigned short h[8];
#pragma unroll
    for (int e = 0; e < 4; ++e) {
        float d = v0[e];
        float q = __builtin_amdgcn_rcpf(d) - inv_mu;
        float s = __expf(q * q * ninv2s2);
        bool keep = (d < 0.5f) & ((jbase + e) != diag);
        h[e] = f2bf(keep ? s : 0.0f);
    }
#pragma unroll
    for (int e = 0; e < 4; ++e) {
        float d = v1[e];
        float q = __builtin_amdgcn_rcpf(d) - inv_mu;
        float s = __expf(q * q * ninv2s2);
        bool keep = (d < 0.5f) & ((jbase + 4 + e) != diag);
        h[4 + e] = f2bf(keep ? s : 0.0f);
    }
    uint4 u;
    u.x = (unsigned)h[0] | ((unsigned)h[1] << 16);
    u.y = (unsigned)h[2] | ((unsigned)h[3] << 16);
    u.z = (unsigned)h[4] | ((unsigned)h[5] << 16);
    u.w = (unsigned)h[6] | ((unsigned)h[7] << 16);
    return __builtin_bit_cast(bf16x8, u);
}

__global__ void __launch_bounds__(64, 2) fused_interact(
    const float* __restrict__ dist, const unsigned short* __restrict__ hT,
    const float* __restrict__ mu, const float* __restrict__ sigma,
    float* __restrict__ part) {
    const int l = threadIdx.x;
    const int ks = (int)blockIdx.x & 7;        // XCD-affine j-slice
    const int rt = (int)blockIdx.x >> 3;       // 0..255
    const int kbeg = ks * (NN / JS);
    const int r0 = rt * 32;

    const int row = l & 15;
    const int kc8 = (l >> 4) << 3;

    const float inv_mu = 1.0f / mu[0];
    const float sg = sigma[0];
    const float ninv2s2 = -1.0f / (2.0f * sg * sg);

    const float* dp0 = dist + (size_t)(r0 + row) * NN + kc8;
    const float* dp1 = dp0 + (size_t)16 * NN;
    const unsigned short* hp = hT + (size_t)row * NN + kc8;
    const int diag0 = r0 + row;
    const int diag1 = diag0 + 16;

    f32x4 acc[2][8];
#pragma unroll
    for (int m = 0; m < 2; ++m)
#pragma unroll
        for (int f = 0; f < 8; ++f) acc[m][f] = (f32x4){0.f, 0.f, 0.f, 0.f};

    // depth-2 rotation slots
    f32x4 s0a, s0b, s0c, s0d, s1a, s1b, s1c, s1d;
    uint4 h0[8], h1[8];

#define LD_DIST(S, K)                                                        \
    do {                                                                     \
        S##a = *(const f32x4*)(dp0 + (K));                                   \
        S##b = *(const f32x4*)(dp0 + (K) + 4);                               \
        S##c = *(const f32x4*)(dp1 + (K));                                   \
        S##d = *(const f32x4*)(dp1 + (K) + 4);                               \
    } while (0)

#define LD_HT(H, K)                                                          \
    do {                                                                     \
        _Pragma("unroll") for (int f = 0; f < 8; ++f)                        \
            H[f] = *(const uint4*)(hp + (size_t)f * 16 * NN + (K));          \
    } while (0)

#define COMPUTE(S, H, K)                                                     \
    do {                                                                     \
        bf16x8 a0 = sfrag(S##a, S##b, (K) + kc8, diag0, inv_mu, ninv2s2);    \
        bf16x8 a1 = sfrag(S##c, S##d, (K) + kc8, diag1, inv_mu, ninv2s2);    \
        _Pragma("unroll") for (int f = 0; f < 8; ++f) {                      \
            bf16x8 bb = __builtin_bit_cast(bf16x8, H[f]);                    \
            acc[0][f] = __builtin_amdgcn_mfma_f32_16x16x32_bf16(             \
                a0, bb, acc[0][f], 0, 0, 0);                                 \
            acc[1][f] = __builtin_amdgcn_mfma_f32_16x16x32_bf16(             \
                a1, bb, acc[1][f], 0, 0, 0);                                 \
        }                                                                    \
    } while (0)

    // prologue: groups 0 and 1
    LD_DIST(s0, kbeg);
    LD_DIST(s1, kbeg + 32);
    LD_HT(h0, kbeg);
    LD_HT(h1, kbeg + 32);

    // steady state: 15 iterations x 2 groups, ALL loads unconditional.
    // iteration at g consumes groups g, g+1 and loads groups g+2, g+3.
#pragma unroll 1
    for (int g = 0; g < 30; g += 2) {
        const int kb = kbeg + (g << 5);
        COMPUTE(s0, h0, kb);
        LD_DIST(s0, kb + 64);
        LD_HT(h0, kb + 64);
        __builtin_amdgcn_sched_barrier(0);
        COMPUTE(s1, h1, kb + 32);
        LD_DIST(s1, kb + 96);
        LD_HT(h1, kb + 96);
        __builtin_amdgcn_sched_barrier(0);
    }
    // peeled tail: groups 30, 31 (already resident in s0/h0, s1/h1)
    COMPUTE(s0, h0, kbeg + 30 * 32);
    COMPUTE(s1, h1, kbeg + 31 * 32);
#undef LD_DIST
#undef LD_HT
#undef COMPUTE

    // epilogue (validated C-layout: col = lane&15, row = (lane>>4)*4 + rr)
    float* po = part + (size_t)ks * (NN * DD);
    const int orow = r0 + ((l >> 4) << 2);
    const int ocol = l & 15;
#pragma unroll
    for (int m = 0; m < 2; ++m)
#pragma unroll
        for (int f = 0; f < 8; ++f)
#pragma unroll
            for (int rr = 0; rr < 4; ++rr)
                po[(size_t)(orow + m * 16 + rr) * DD + f * 16 + ocol] =
                    acc[m][f][rr];
}

// ---------------------------------------------------------------------------
// Kernel C: sum the 8 K-split partials into out.
// ---------------------------------------------------------------------------
__global__ void __launch_bounds__(256) reduce_part(
    const float* __restrict__ part, float* __restrict__ outp) {
    const size_t idx = ((size_t)blockIdx.x * 256 + threadIdx.x) << 2;
    f32x4 s = *(const f32x4*)(part + idx);
#pragma unroll
    for (int ksp = 1; ksp < JS; ++ksp)
        s += *(const f32x4*)(part + (size_t)ksp * (NN * DD) + idx);
    *(f32x4*)(outp + idx) = s;
}

extern "C" void kernel_launch(void* const* d_in, const int* in_sizes, int n_in,
                              void* d_out, int out_size, void* d_ws, size_t ws_size,
                              hipStream_t stream) {
    const float* z = (const float*)d_in[0];
    const float* dist = (const float*)d_in[1];
    const float* W = (const float*)d_in[2];
    const float* Bv = (const float*)d_in[3];
    const float* mu = (const float*)d_in[4];
    const float* sigma = (const float*)d_in[5];
    float* out = (float*)d_out;

    unsigned short* hT = (unsigned short*)d_ws;                 // 2 MB
    const size_t hT_bytes = (size_t)DD * NN * 2;
    float* part = (float*)((char*)d_ws + hT_bytes);             // 8 x 4 MB

    h_transform<<<NN / BM, 256, 0, stream>>>(z, W, Bv, hT);
    fused_interact<<<(NN / 32) * JS, 64, 0, stream>>>(dist, hT, mu, sigma,
                                                      part);
    reduce_part<<<(NN * DD) / 1024, 256, 0, stream>>>(part, out);
}

// Round 9
// 127.296 us; speedup vs baseline: 1.1545x; 1.1005x over previous
//
#include <hip/hip_runtime.h>
#include <hip/hip_bf16.h>

#define NN 8192
#define DD 128
#define BM 16
#define JS 8            // j-slices (K-split of the reduction), XCD-affine

typedef __attribute__((ext_vector_type(4))) float f32x4;
typedef __attribute__((ext_vector_type(8))) short bf16x8;
typedef __attribute__((ext_vector_type(4))) unsigned int u32x4;

__device__ __forceinline__ unsigned short f2bf(float x) {
    unsigned u = __float_as_uint(x);
    u += 0x7fffu + ((u >> 16) & 1u);   // round-to-nearest-even
    return (unsigned short)(u >> 16);
}

// ---------------------------------------------------------------------------
// Kernel A: h = z@W + B, stored PACKED fragment-linear:
//   element (n, j) -> hT[(j>>5)*4096 + (n>>4)*512 + ((j>>3)&3)*128
//                        + (n&15)*8 + (j&7)]
// so that lane l, fragment f of K-group kt reads its 8 bf16 B-frag at
// kt*4096 + f*512 + l*8  -- a fully coalesced 1 KB load per fragment.
// ---------------------------------------------------------------------------
__global__ void __launch_bounds__(256) h_transform(
    const float* __restrict__ z, const float* __restrict__ W,
    const float* __restrict__ Bv, unsigned short* __restrict__ hT) {
    __shared__ float zs[BM * DD];
    __shared__ float wt[DD * 132];
    const int t = threadIdx.x;
    const int j0 = blockIdx.x * BM;

    {
        const f32x4* zsrc = (const f32x4*)(z + (size_t)j0 * DD);
        f32x4* zdst = (f32x4*)zs;
        zdst[t] = zsrc[t];
        zdst[t + 256] = zsrc[t + 256];
    }
    for (int q = t; q < DD * 32; q += 256) {
        int k = q >> 5;
        int n0 = (q & 31) << 2;
        f32x4 wv = *(const f32x4*)(W + k * DD + n0);
        wt[(n0 + 0) * 132 + k] = wv[0];
        wt[(n0 + 1) * 132 + k] = wv[1];
        wt[(n0 + 2) * 132 + k] = wv[2];
        wt[(n0 + 3) * 132 + k] = wv[3];
    }
    __syncthreads();

    const int n = t >> 1;
    const int ja = (t & 1) << 3;
    float acc[8];
    float bn = Bv[n];
#pragma unroll
    for (int e = 0; e < 8; e++) acc[e] = bn;

#pragma unroll 8
    for (int k4 = 0; k4 < 32; ++k4) {
        f32x4 wv = *(const f32x4*)&wt[n * 132 + (k4 << 2)];
#pragma unroll
        for (int e = 0; e < 8; e++) {
            f32x4 zv = *(const f32x4*)&zs[(ja + e) * DD + (k4 << 2)];
            acc[e] += zv[0] * wv[0] + zv[1] * wv[1] + zv[2] * wv[2] + zv[3] * wv[3];
        }
    }

    const int j = j0 + ja;       // 8-aligned
    unsigned short* dst = hT + ((j >> 5) * 4096 + (n >> 4) * 512 +
                                (((j >> 3) & 3) << 7) + ((n & 15) << 3));
    uint4 uv;
    uv.x = (unsigned)f2bf(acc[0]) | ((unsigned)f2bf(acc[1]) << 16);
    uv.y = (unsigned)f2bf(acc[2]) | ((unsigned)f2bf(acc[3]) << 16);
    uv.z = (unsigned)f2bf(acc[4]) | ((unsigned)f2bf(acc[5]) << 16);
    uv.w = (unsigned)f2bf(acc[6]) | ((unsigned)f2bf(acc[7]) << 16);
    *(uint4*)dst = uv;
}

// ---------------------------------------------------------------------------
// Kernel B: fused S + S@h, DRAM-friendly dist streaming.
// 1-wave blocks, 16 rows x 1024-j-slice (ks = bid&7 -> XCD-affine hT L2).
// Per superchunk of K=256: 16 dist loads, each a 1 KB CONTIGUOUS run of one
// row (lane l reads 16 B at col 4l); rows advance j sequentially -> >=1 KB
// DRAM granules (vs 128 B fragment-scatter of rounds 1-8 = the 1.3 TB/s
// page-thrash wall). S computed in-register, redistributed to the validated
// A-frag layout via WAVE-PRIVATE LDS (no __syncthreads anywhere):
//   element block (p,q,h) of group g at byte g*1056 + (4p+q)*16 + 8h
//   (write: <=4-way bank conflict; read: b128 conflict-free, lane L at
//    g*1056 + (4*(L&15) + (L>>4))*16).
// hT B-frags from packed layout, depth-3 register slot rotation. Both loops
// fully unrolled -> straight-line, unconditional loads, static indices.
// ---------------------------------------------------------------------------
__global__ void __launch_bounds__(64, 2) fused_interact(
    const float* __restrict__ dist, const unsigned short* __restrict__ hT,
    const float* __restrict__ mu, const float* __restrict__ sigma,
    float* __restrict__ part) {
    __shared__ char sfr[8 * 1056];     // 8 groups x 1056 B, wave-private
    const int l = threadIdx.x;
    const int ks = (int)blockIdx.x & 7;
    const int rt = (int)blockIdx.x >> 3;       // 0..511
    const int kbeg = ks * (NN / JS);
    const int r0 = rt * 16;

    const float inv_mu = 1.0f / mu[0];
    const float sg = sigma[0];
    const float ninv2s2 = -1.0f / (2.0f * sg * sg);

    const float* dbase = dist + (size_t)r0 * NN + kbeg + 4 * l;
    const unsigned short* hp = hT + (size_t)(kbeg >> 5) * 4096 + l * 8;

    const int ard = (4 * (l & 15) + (l >> 4)) * 16;               // A-frag read
    const int awr = (l >> 3) * 1056 + ((l & 7) >> 1) * 16 + (l & 1) * 8;
    const int colb = kbeg + 4 * l;

    f32x4 acc[8];
#pragma unroll
    for (int f = 0; f < 8; ++f) acc[f] = (f32x4){0.f, 0.f, 0.f, 0.f};

    f32x4 dv[16];
    u32x4 hS[3][8];

#define LDDIST(SC)                                                           \
    do {                                                                     \
        _Pragma("unroll") for (int p = 0; p < 16; ++p)                       \
            dv[p] = *(const f32x4*)(dbase + (size_t)p * NN + (SC) * 256);    \
    } while (0)

#define LDHT(SLOT, KT)                                                       \
    do {                                                                     \
        _Pragma("unroll") for (int f = 0; f < 8; ++f)                        \
            hS[SLOT][f] = *(const u32x4*)(hp + (KT) * 4096 + f * 512);       \
    } while (0)

    // prologue: dist superchunk 0; hT groups 0..2
    LDDIST(0);
    LDHT(0, 0);
    LDHT(1, 1);
    LDHT(2, 2);

#pragma unroll
    for (int sc = 0; sc < 4; ++sc) {
        // ---- S-phase: 16 rows -> LDS (fragment-permuted layout) ----
#pragma unroll
        for (int p = 0; p < 16; ++p) {
            const int rg = r0 + p;
            unsigned short hh[4];
#pragma unroll
            for (int e = 0; e < 4; ++e) {
                float d = dv[p][e];
                float qq = __builtin_amdgcn_rcpf(d) - inv_mu;
                float s = __expf(qq * qq * ninv2s2);
                bool keep = (d < 0.5f) & ((colb + sc * 256 + e) != rg);
                hh[e] = f2bf(keep ? s : 0.0f);
            }
            uint2 u;
            u.x = (unsigned)hh[0] | ((unsigned)hh[1] << 16);
            u.y = (unsigned)hh[2] | ((unsigned)hh[3] << 16);
            *(uint2*)(sfr + awr + p * 64) = u;
        }
        // prefetch next dist superchunk (compile-time condition: unrolled)
        if (sc < 3) LDDIST(sc + 1);

        // ---- MFMA phase: 8 groups of K=32 ----
#pragma unroll
        for (int g = 0; g < 8; ++g) {
            const int kt = sc * 8 + g;
            bf16x8 a = *(const bf16x8*)(sfr + g * 1056 + ard);
#pragma unroll
            for (int f = 0; f < 8; ++f)
                acc[f] = __builtin_amdgcn_mfma_f32_16x16x32_bf16(
                    a, __builtin_bit_cast(bf16x8, hS[kt % 3][f]), acc[f],
                    0, 0, 0);
            if (kt + 3 < 32) LDHT((kt + 3) % 3, kt + 3);
        }
    }
#undef LDDIST
#undef LDHT

    // epilogue (validated C-layout: col = lane&15, row = (lane>>4)*4 + rr)
    float* po = part + (size_t)ks * (NN * DD);
    const int orow = r0 + ((l >> 4) << 2);
    const int ocol = l & 15;
#pragma unroll
    for (int f = 0; f < 8; ++f)
#pragma unroll
        for (int rr = 0; rr < 4; ++rr)
            po[(size_t)(orow + rr) * DD + f * 16 + ocol] = acc[f][rr];
}

// ---------------------------------------------------------------------------
// Kernel C: sum the 8 K-split partials into out.
// ---------------------------------------------------------------------------
__global__ void __launch_bounds__(256) reduce_part(
    const float* __restrict__ part, float* __restrict__ outp) {
    const size_t idx = ((size_t)blockIdx.x * 256 + threadIdx.x) << 2;
    f32x4 s = *(const f32x4*)(part + idx);
#pragma unroll
    for (int ksp = 1; ksp < JS; ++ksp)
        s += *(const f32x4*)(part + (size_t)ksp * (NN * DD) + idx);
    *(f32x4*)(outp + idx) = s;
}

extern "C" void kernel_launch(void* const* d_in, const int* in_sizes, int n_in,
                              void* d_out, int out_size, void* d_ws, size_t ws_size,
                              hipStream_t stream) {
    const float* z = (const float*)d_in[0];
    const float* dist = (const float*)d_in[1];
    const float* W = (const float*)d_in[2];
    const float* Bv = (const float*)d_in[3];
    const float* mu = (const float*)d_in[4];
    const float* sigma = (const float*)d_in[5];
    float* out = (float*)d_out;

    unsigned short* hT = (unsigned short*)d_ws;                 // 2 MB packed
    const size_t hT_bytes = (size_t)DD * NN * 2;
    float* part = (float*)((char*)d_ws + hT_bytes);             // 8 x 4 MB

    h_transform<<<NN / BM, 256, 0, stream>>>(z, W, Bv, hT);
    fused_interact<<<(NN / 16) * JS, 64, 0, stream>>>(dist, hT, mu, sigma,
                                                      part);
    reduce_part<<<(NN * DD) / 1024, 256, 0, stream>>>(part, out);
}